// Round 7
// baseline (166.441 us; speedup 1.0000x reference)
//
#include <hip/hip_runtime.h>
#include <hip/hip_bf16.h>
#include <math.h>

typedef short short8 __attribute__((ext_vector_type(8)));
typedef float floatx4 __attribute__((ext_vector_type(4)));

#define NB 4096
#define DD 128
static constexpr float EPSF = 1e-8f;
static constexpr float TEMP = 11.313708498984760390f; // sqrt(128)

static __device__ __forceinline__ short f2bf(float f) {
    __hip_bfloat16 h = __float2bfloat16(f);
    union { __hip_bfloat16 h; short s; } u; u.h = h; return u.s;
}
static __device__ __forceinline__ float bf2f(short s) {
    union { __hip_bfloat16 h; short s; } u; u.s = s;
    return __bfloat162float(u.h);
}

// Pack 8 consecutive fp32 -> bf16x8 fragment
static __device__ __forceinline__ short8 load_cvt8(const float* __restrict__ p) {
    float4 a = *(const float4*)p;
    float4 b = *(const float4*)(p + 4);
    short8 o;
    o[0] = f2bf(a.x); o[1] = f2bf(a.y); o[2] = f2bf(a.z); o[3] = f2bf(a.w);
    o[4] = f2bf(b.x); o[5] = f2bf(b.y); o[6] = f2bf(b.z); o[7] = f2bf(b.w);
    return o;
}

// Fragment-major offset for qn/kn: matrix row g (0..4095), k index kidx (0..127)
// layout: [g>>4][kidx>>5][(kidx>>3)&3 * 16 + (g&15)][kidx&7]
static __device__ __forceinline__ int frag_off(int g, int kidx) {
    return ((((g >> 4) * 4 + (kidx >> 5)) * 4 + ((kidx >> 3) & 3)) * 16
            + (g & 15)) * 8 + (kidx & 7);
}

// ---------------- projection + metric-normalize (MFMA, bf16) ----------------
// R4/R6-passing version, unchanged. 512 blocks x 512 threads.
__global__ __launch_bounds__(512) void proj_kernel(
    const float* __restrict__ qp, const float* __restrict__ kp,
    const float* __restrict__ Wq, const float* __restrict__ bq,
    const float* __restrict__ Wk, const float* __restrict__ bk,
    __hip_bfloat16* __restrict__ qn, __hip_bfloat16* __restrict__ kn,
    float* __restrict__ rq, float* __restrict__ rk)
{
    int t = threadIdx.x;
    int b = blockIdx.x;                 // 0..511; 256 per matrix

    int which = b >> 8;
    int row0 = (b & 255) * 16;
    const float* x    = which ? kp : qp;
    const float* W    = which ? Wk : Wq;
    const float* bias = which ? bk : bq;
    short* outv = which ? (short*)kn : (short*)qn;
    float* outr = which ? rk : rq;

    int lane = t & 63, wid = t >> 6;    // 8 waves
    int m = lane & 15, quad = lane >> 4;
    int colb = wid * 16;                // wave col origin (8 waves x 16 cols)

    floatx4 acc = (floatx4){0.f, 0.f, 0.f, 0.f};

    #pragma unroll
    for (int ks = 0; ks < 4; ++ks) {
        int koff = ks * 32 + quad * 8;
        short8 af  = load_cvt8(x + (row0 + m) * DD + koff);
        short8 bfr = load_cvt8(W + (colb + m) * DD + koff);
        acc = __builtin_amdgcn_mfma_f32_16x16x32_bf16(af, bfr, acc, 0, 0, 0);
    }

    __shared__ float buf[8][16];
    __shared__ float nfb[16];

    float bv = bias[colb + m];

    #pragma unroll
    for (int r = 0; r < 4; ++r) {
        float v = acc[r] + bv;
        acc[r] = v;
        float p = v * v;
        p += __shfl_xor(p, 1); p += __shfl_xor(p, 2);
        p += __shfl_xor(p, 4); p += __shfl_xor(p, 8);
        if (m == 0) buf[wid][quad*4 + r] = p;
    }
    __syncthreads();
    if (t < 16) {
        float s = 0.f;
        #pragma unroll
        for (int w = 0; w < 8; ++w) s += buf[w][t];
        float fro = sqrtf(s*s*(1.0f/16384.0f) + s*(1.0f/64.0f) + 128.0f);
        float qnorm = sqrtf((s*s*(1.0f/128.0f) + s) / (fro + EPSF));
        nfb[t] = 1.0f / (qnorm + EPSF);
    }
    __syncthreads();

    #pragma unroll
    for (int r = 0; r < 4; ++r) {
        int lrow = quad*4 + r;              // block-local 0..15
        int g = row0 + lrow;                // global matrix row
        float nf = nfb[lrow];
        float v = acc[r] * nf;
        short sb = f2bf(v);
        outv[frag_off(g, colb + m)] = sb;
        float vf = bf2f(sb);
        float u = vf * vf;
        u += __shfl_xor(u, 1); u += __shfl_xor(u, 2);
        u += __shfl_xor(u, 4); u += __shfl_xor(u, 8);
        if (m == 0) buf[wid][lrow] = u;
    }
    __syncthreads();
    if (t < 16) {
        float s = 0.f;
        #pragma unroll
        for (int w = 0; w < 8; ++w) s += buf[w][t];
        outr[row0 + t] = s;
    }
}

// ---------------- scores, decoupled into two full-occupancy kernels ---------
// R6 post-mortem: every score variant (acc-spill, acc-in-AGPR, two-pass) ran
// ~44.5 us with NOTHING saturated (VALU 27%, MFMA 7%, HBM 27%) -- latency-
// bound at 16 waves/CU, pinned there because the softmax denominator forced
// one 1024-thread block to own a full 4096-col row-set (256 blocks = 1/CU).
// Fix: break the coupling with a kernel boundary. row_sums computes partial
// row sums at 1024 blocks x 512 thr (4 blocks/CU = 32 waves/CU, 2x the wave
// capacity) -> device atomicAdd into rsg[4096] (4 addends/row, ~1e-7 rel
// nondeterminism, absmax margin 10x). score_store recomputes bit-identical e
// at the same full-occupancy geometry and stores e*inv directly.
// __launch_bounds__(512, 8) caps at 64 VGPR (live state ~50: af 16 + bfr 16
// + addr/temps) so 4 blocks/CU is register-feasible.

// Block b: rowset = b>>2 (16 rows), colseg = b&3 (1024 cols).
// Wave w (0..7) owns cols [colseg*1024 + w*128, +128) = 8 tiles of 16 cols.
// mfma(bfr, af): lane (m,quad) owns q-row (r0+m), k-cols colblk*16+quad*4+r.
__global__ __launch_bounds__(512, 8) void row_sums(
    const __hip_bfloat16* __restrict__ qn, const __hip_bfloat16* __restrict__ kn,
    const float* __restrict__ rq, const float* __restrict__ rk,
    float* __restrict__ rsg)
{
    int tid  = threadIdx.x;
    int lane = tid & 63;
    int wid  = tid >> 6;                // 0..7
    int m    = lane & 15;
    int quad = lane >> 4;

    int b      = blockIdx.x;            // 0..1023
    int rowset = b >> 2;                // 0..255
    int colseg = b & 3;                 // 1024-col segment
    int r0 = rowset * 16;
    int cs = colseg * 1024 + wid * 128; // wave's 128-col strip

    const short* qs  = (const short*)qn;
    const short* kks = (const short*)kn;

    short8 af[4];
    #pragma unroll
    for (int k4 = 0; k4 < 4; ++k4)
        af[k4] = *(const short8*)(qs + ((rowset*4 + k4)*64 + lane)*8);

    float rqv = rq[r0 + m];

    float rs = 0.f;
    #pragma unroll
    for (int t = 0; t < 8; ++t) {
        int colblk = (cs >> 4) + t;
        short8 bfr[4];
        #pragma unroll
        for (int k4 = 0; k4 < 4; ++k4)
            bfr[k4] = *(const short8*)(kks + ((colblk*4 + k4)*64 + lane)*8);
        floatx4 a = (floatx4){0.f, 0.f, 0.f, 0.f};
        #pragma unroll
        for (int k4 = 0; k4 < 4; ++k4)
            a = __builtin_amdgcn_mfma_f32_16x16x32_bf16(bfr[k4], af[k4], a, 0, 0, 0);
        floatx4 rkv = *(const floatx4*)(rk + colblk*16 + quad*4);
        #pragma unroll
        for (int r = 0; r < 4; ++r) {
            float d2 = fmaf(-2.0f, a[r], rqv + rkv[r]);
            float d  = d2 > 0.0f ? __builtin_amdgcn_sqrtf(d2) : 0.0f;
            float e  = __expf(TEMP * __builtin_amdgcn_rcpf(1.0f + d));
            rs += e;
        }
    }

    // reduce across the 4 quads -> lanes of equal m hold the 128-col partial
    rs += __shfl_xor(rs, 16);
    rs += __shfl_xor(rs, 32);

    __shared__ float sums[8][16];
    if (lane < 16) sums[wid][lane] = rs;
    __syncthreads();
    if (tid < 16) {
        float s = 0.f;
        #pragma unroll
        for (int w = 0; w < 8; ++w) s += sums[w][tid];
        atomicAdd(&rsg[r0 + tid], s);   // device-scope by default on gfx950
    }
}

__global__ __launch_bounds__(512, 8) void score_store(
    const __hip_bfloat16* __restrict__ qn, const __hip_bfloat16* __restrict__ kn,
    const float* __restrict__ rq, const float* __restrict__ rk,
    const float* __restrict__ rsg, float* __restrict__ P)
{
    int tid  = threadIdx.x;
    int lane = tid & 63;
    int wid  = tid >> 6;                // 0..7
    int m    = lane & 15;
    int quad = lane >> 4;

    int b      = blockIdx.x;            // 0..1023
    int rowset = b >> 2;
    int colseg = b & 3;
    int r0 = rowset * 16;
    int cs = colseg * 1024 + wid * 128;

    const short* qs  = (const short*)qn;
    const short* kks = (const short*)kn;

    short8 af[4];
    #pragma unroll
    for (int k4 = 0; k4 < 4; ++k4)
        af[k4] = *(const short8*)(qs + ((rowset*4 + k4)*64 + lane)*8);

    float rqv  = rq[r0 + m];
    float invv = __builtin_amdgcn_rcpf(rsg[r0 + m] + EPSF);

    #pragma unroll
    for (int t = 0; t < 8; ++t) {
        int colblk = (cs >> 4) + t;
        short8 bfr[4];
        #pragma unroll
        for (int k4 = 0; k4 < 4; ++k4)
            bfr[k4] = *(const short8*)(kks + ((colblk*4 + k4)*64 + lane)*8);
        floatx4 a = (floatx4){0.f, 0.f, 0.f, 0.f};
        #pragma unroll
        for (int k4 = 0; k4 < 4; ++k4)
            a = __builtin_amdgcn_mfma_f32_16x16x32_bf16(bfr[k4], af[k4], a, 0, 0, 0);
        floatx4 rkv = *(const floatx4*)(rk + colblk*16 + quad*4);
        floatx4 o;
        #pragma unroll
        for (int r = 0; r < 4; ++r) {
            float d2 = fmaf(-2.0f, a[r], rqv + rkv[r]);
            float d  = d2 > 0.0f ? __builtin_amdgcn_sqrtf(d2) : 0.0f;
            float e  = __expf(TEMP * __builtin_amdgcn_rcpf(1.0f + d));
            o[r] = e * invv;
        }
        *(floatx4*)(P + (size_t)(r0 + m) * NB + colblk*16 + quad*4) = o;
    }
}

extern "C" void kernel_launch(void* const* d_in, const int* in_sizes, int n_in,
                              void* d_out, int out_size, void* d_ws, size_t ws_size,
                              hipStream_t stream) {
    const float* qp = (const float*)d_in[0];
    const float* kp = (const float*)d_in[1];
    const float* Wq = (const float*)d_in[2];
    const float* bq = (const float*)d_in[3];
    const float* Wk = (const float*)d_in[4];
    const float* bk = (const float*)d_in[5];
    float* P = (float*)d_out;

    char* ws = (char*)d_ws;
    __hip_bfloat16* qn = (__hip_bfloat16*)ws;                         // 1 MB
    __hip_bfloat16* kn = (__hip_bfloat16*)(ws + (size_t)NB*DD*2);     // 1 MB
    float* rq  = (float*)(ws + (size_t)NB*DD*4);                      // 16 KB
    float* rk  = (float*)(ws + (size_t)NB*DD*4 + (size_t)NB*4);       // 16 KB
    float* rsg = (float*)(ws + (size_t)NB*DD*4 + (size_t)NB*8);       // 16 KB

    // zero the row-sum accumulator (stream-ordered, graph-capturable)
    hipMemsetAsync(rsg, 0, (size_t)NB * sizeof(float), stream);

    hipLaunchKernelGGL(proj_kernel, dim3(512), dim3(512), 0, stream,
                       qp, kp, Wq, bq, Wk, bk, qn, kn, rq, rk);
    hipLaunchKernelGGL(row_sums, dim3(1024), dim3(512), 0, stream,
                       qn, kn, rq, rk, rsg);
    hipLaunchKernelGGL(score_store, dim3(1024), dim3(512), 0, stream,
                       qn, kn, rq, rk, rsg, P);
}

// Round 8
// 124.627 us; speedup vs baseline: 1.3355x; 1.3355x over previous
//
#include <hip/hip_runtime.h>
#include <hip/hip_bf16.h>
#include <math.h>

typedef short short8 __attribute__((ext_vector_type(8)));
typedef float floatx4 __attribute__((ext_vector_type(4)));

#define NB 4096
#define DD 128
static constexpr float EPSF = 1e-8f;
static constexpr float TEMP = 11.313708498984760390f; // sqrt(128)

static __device__ __forceinline__ short f2bf(float f) {
    __hip_bfloat16 h = __float2bfloat16(f);
    union { __hip_bfloat16 h; short s; } u; u.h = h; return u.s;
}
static __device__ __forceinline__ float bf2f(short s) {
    union { __hip_bfloat16 h; short s; } u; u.s = s;
    return __bfloat162float(u.h);
}

// Pack 8 consecutive fp32 -> bf16x8 fragment
static __device__ __forceinline__ short8 load_cvt8(const float* __restrict__ p) {
    float4 a = *(const float4*)p;
    float4 b = *(const float4*)(p + 4);
    short8 o;
    o[0] = f2bf(a.x); o[1] = f2bf(a.y); o[2] = f2bf(a.z); o[3] = f2bf(a.w);
    o[4] = f2bf(b.x); o[5] = f2bf(b.y); o[6] = f2bf(b.z); o[7] = f2bf(b.w);
    return o;
}

// Fragment-major offset for qn/kn: matrix row g (0..4095), k index kidx (0..127)
// layout: [g>>4][kidx>>5][(kidx>>3)&3 * 16 + (g&15)][kidx&7]
static __device__ __forceinline__ int frag_off(int g, int kidx) {
    return ((((g >> 4) * 4 + (kidx >> 5)) * 4 + ((kidx >> 3) & 3)) * 16
            + (g & 15)) * 8 + (kidx & 7);
}

// ---------------- projection + metric-normalize (MFMA, bf16) ----------------
// R4/R6-passing version, unchanged. 512 blocks x 512 threads.
__global__ __launch_bounds__(512) void proj_kernel(
    const float* __restrict__ qp, const float* __restrict__ kp,
    const float* __restrict__ Wq, const float* __restrict__ bq,
    const float* __restrict__ Wk, const float* __restrict__ bk,
    __hip_bfloat16* __restrict__ qn, __hip_bfloat16* __restrict__ kn,
    float* __restrict__ rq, float* __restrict__ rk)
{
    int t = threadIdx.x;
    int b = blockIdx.x;                 // 0..511; 256 per matrix

    int which = b >> 8;
    int row0 = (b & 255) * 16;
    const float* x    = which ? kp : qp;
    const float* W    = which ? Wk : Wq;
    const float* bias = which ? bk : bq;
    short* outv = which ? (short*)kn : (short*)qn;
    float* outr = which ? rk : rq;

    int lane = t & 63, wid = t >> 6;    // 8 waves
    int m = lane & 15, quad = lane >> 4;
    int colb = wid * 16;                // wave col origin (8 waves x 16 cols)

    floatx4 acc = (floatx4){0.f, 0.f, 0.f, 0.f};

    #pragma unroll
    for (int ks = 0; ks < 4; ++ks) {
        int koff = ks * 32 + quad * 8;
        short8 af  = load_cvt8(x + (row0 + m) * DD + koff);
        short8 bfr = load_cvt8(W + (colb + m) * DD + koff);
        acc = __builtin_amdgcn_mfma_f32_16x16x32_bf16(af, bfr, acc, 0, 0, 0);
    }

    __shared__ float buf[8][16];
    __shared__ float nfb[16];

    float bv = bias[colb + m];

    #pragma unroll
    for (int r = 0; r < 4; ++r) {
        float v = acc[r] + bv;
        acc[r] = v;
        float p = v * v;
        p += __shfl_xor(p, 1); p += __shfl_xor(p, 2);
        p += __shfl_xor(p, 4); p += __shfl_xor(p, 8);
        if (m == 0) buf[wid][quad*4 + r] = p;
    }
    __syncthreads();
    if (t < 16) {
        float s = 0.f;
        #pragma unroll
        for (int w = 0; w < 8; ++w) s += buf[w][t];
        float fro = sqrtf(s*s*(1.0f/16384.0f) + s*(1.0f/64.0f) + 128.0f);
        float qnorm = sqrtf((s*s*(1.0f/128.0f) + s) / (fro + EPSF));
        nfb[t] = 1.0f / (qnorm + EPSF);
    }
    __syncthreads();

    #pragma unroll
    for (int r = 0; r < 4; ++r) {
        int lrow = quad*4 + r;              // block-local 0..15
        int g = row0 + lrow;                // global matrix row
        float nf = nfb[lrow];
        float v = acc[r] * nf;
        short sb = f2bf(v);
        outv[frag_off(g, colb + m)] = sb;
        float vf = bf2f(sb);
        float u = vf * vf;
        u += __shfl_xor(u, 1); u += __shfl_xor(u, 2);
        u += __shfl_xor(u, 4); u += __shfl_xor(u, 8);
        if (m == 0) buf[wid][lrow] = u;
    }
    __syncthreads();
    if (t < 16) {
        float s = 0.f;
        #pragma unroll
        for (int w = 0; w < 8; ++w) s += buf[w][t];
        outr[row0 + t] = s;
    }
}

// ---------------- scores: two-pass recompute + manual 1-deep pipeline -------
// 256 blocks x 1024 threads (16 waves, bounds(1024,4) -> 128-reg budget;
// R7 proved any tighter budget spills catastrophically). Wave w owns cols
// [w*256, w*256+256): 16 tiles of 16 cols. mfma(bfr, af): lane (m,quad) owns
// q-row (r0+m), k-cols colblk*16+quad*4+r.
//
// R6 post-mortem: two-pass left ~70 regs of headroom but the compiler only
// pipelined bfr loads ~1 tile deep on its own (VALU 27%, MFMA 6.7%, nothing
// saturated -> exposed ~300cy L2 latency per tile). This version EXPLICITLY
// rotates bcur/bnxt (+ rkv) one tile ahead in both passes: next tile's 4x16B
// loads issue before the current tile's MFMA+transcendental work, so with
// 4 waves/SIMD the latency is covered. All array indices compile-time
// (full unroll) -> registers, no scratch.
__global__ __launch_bounds__(1024, 4) void score_rows(
    const __hip_bfloat16* __restrict__ qn, const __hip_bfloat16* __restrict__ kn,
    const float* __restrict__ rq, const float* __restrict__ rk,
    float* __restrict__ P)
{
    int lane = threadIdx.x & 63;
    int wid  = threadIdx.x >> 6;        // 0..15
    int m    = lane & 15;
    int quad = lane >> 4;

    int rowblk = blockIdx.x;            // 16 rows per block
    int r0 = rowblk * 16;
    int cb0 = wid * 16;                 // wave's first colblk (cols wid*256..)

    const short* qs  = (const short*)qn;
    const short* kks = (const short*)kn;

    // A fragments: 16 rows x K=128 (coalesced 1 KB loads)
    short8 af[4];
    #pragma unroll
    for (int k4 = 0; k4 < 4; ++k4)
        af[k4] = *(const short8*)(qs + ((rowblk*4 + k4)*64 + lane)*8);

    float rqv = rq[r0 + m];             // this lane's q-row |qn|^2

    // ---------------- pass A: row sums only (e discarded) ----------------
    float rs = 0.f;
    {
        short8 bcur[4], bnxt[4];
        #pragma unroll
        for (int k4 = 0; k4 < 4; ++k4)
            bcur[k4] = *(const short8*)(kks + ((cb0*4 + k4)*64 + lane)*8);
        floatx4 rkc = *(const floatx4*)(rk + cb0*16 + quad*4);

        #pragma unroll
        for (int t = 0; t < 16; ++t) {
            floatx4 rkn;
            if (t < 15) {
                int nb = cb0 + t + 1;
                #pragma unroll
                for (int k4 = 0; k4 < 4; ++k4)
                    bnxt[k4] = *(const short8*)(kks + ((nb*4 + k4)*64 + lane)*8);
                rkn = *(const floatx4*)(rk + nb*16 + quad*4);
            }
            floatx4 a = (floatx4){0.f, 0.f, 0.f, 0.f};
            #pragma unroll
            for (int k4 = 0; k4 < 4; ++k4)
                a = __builtin_amdgcn_mfma_f32_16x16x32_bf16(bcur[k4], af[k4], a, 0, 0, 0);
            #pragma unroll
            for (int r = 0; r < 4; ++r) {
                float d2 = fmaf(-2.0f, a[r], rqv + rkc[r]);
                float d  = d2 > 0.0f ? __builtin_amdgcn_sqrtf(d2) : 0.0f;
                float e  = __expf(TEMP * __builtin_amdgcn_rcpf(1.0f + d));
                rs += e;
            }
            if (t < 15) {
                #pragma unroll
                for (int k4 = 0; k4 < 4; ++k4) bcur[k4] = bnxt[k4];
                rkc = rkn;
            }
        }
    }

    // rs is partial over this lane's 64 cols; reduce across the 4 quads
    rs += __shfl_xor(rs, 16);
    rs += __shfl_xor(rs, 32);

    __shared__ float sums[16][16];
    __shared__ float inv[16];
    if (lane < 16) sums[wid][lane] = rs;   // quad==0 lanes: m = lane
    __syncthreads();
    if (threadIdx.x < 16) {
        float s = 0.f;
        #pragma unroll
        for (int w = 0; w < 16; ++w) s += sums[w][threadIdx.x];
        inv[threadIdx.x] = __builtin_amdgcn_rcpf(s + EPSF);
    }
    __syncthreads();

    float invv = inv[m];

    // ---------------- pass B: recompute e, scale, store ------------------
    // Same inputs + same op order as pass A -> bit-identical e.
    {
        short8 bcur[4], bnxt[4];
        #pragma unroll
        for (int k4 = 0; k4 < 4; ++k4)
            bcur[k4] = *(const short8*)(kks + ((cb0*4 + k4)*64 + lane)*8);
        floatx4 rkc = *(const floatx4*)(rk + cb0*16 + quad*4);

        #pragma unroll
        for (int t = 0; t < 16; ++t) {
            int colblk = cb0 + t;
            floatx4 rkn;
            if (t < 15) {
                int nb = colblk + 1;
                #pragma unroll
                for (int k4 = 0; k4 < 4; ++k4)
                    bnxt[k4] = *(const short8*)(kks + ((nb*4 + k4)*64 + lane)*8);
                rkn = *(const floatx4*)(rk + nb*16 + quad*4);
            }
            floatx4 a = (floatx4){0.f, 0.f, 0.f, 0.f};
            #pragma unroll
            for (int k4 = 0; k4 < 4; ++k4)
                a = __builtin_amdgcn_mfma_f32_16x16x32_bf16(bcur[k4], af[k4], a, 0, 0, 0);
            floatx4 o;
            #pragma unroll
            for (int r = 0; r < 4; ++r) {
                float d2 = fmaf(-2.0f, a[r], rqv + rkc[r]);
                float d  = d2 > 0.0f ? __builtin_amdgcn_sqrtf(d2) : 0.0f;
                float e  = __expf(TEMP * __builtin_amdgcn_rcpf(1.0f + d));
                o[r] = e * invv;
            }
            *(floatx4*)(P + (size_t)(r0 + m) * NB + colblk*16 + quad*4) = o;
            if (t < 15) {
                #pragma unroll
                for (int k4 = 0; k4 < 4; ++k4) bcur[k4] = bnxt[k4];
                rkc = rkn;
            }
        }
    }
}

extern "C" void kernel_launch(void* const* d_in, const int* in_sizes, int n_in,
                              void* d_out, int out_size, void* d_ws, size_t ws_size,
                              hipStream_t stream) {
    const float* qp = (const float*)d_in[0];
    const float* kp = (const float*)d_in[1];
    const float* Wq = (const float*)d_in[2];
    const float* bq = (const float*)d_in[3];
    const float* Wk = (const float*)d_in[4];
    const float* bk = (const float*)d_in[5];
    float* P = (float*)d_out;

    char* ws = (char*)d_ws;
    __hip_bfloat16* qn = (__hip_bfloat16*)ws;                         // 1 MB
    __hip_bfloat16* kn = (__hip_bfloat16*)(ws + (size_t)NB*DD*2);     // 1 MB
    float* rq = (float*)(ws + (size_t)NB*DD*4);                       // 16 KB
    float* rk = (float*)(ws + (size_t)NB*DD*4 + (size_t)NB*4);        // 16 KB

    hipLaunchKernelGGL(proj_kernel, dim3(512), dim3(512), 0, stream,
                       qp, kp, Wq, bq, Wk, bk, qn, kn, rq, rk);
    hipLaunchKernelGGL(score_rows, dim3(256), dim3(1024), 0, stream,
                       qn, kn, rq, rk, P);
}

// Round 9
// 121.872 us; speedup vs baseline: 1.3657x; 1.0226x over previous
//
#include <hip/hip_runtime.h>
#include <hip/hip_bf16.h>
#include <math.h>

typedef short short8 __attribute__((ext_vector_type(8)));
typedef float floatx4 __attribute__((ext_vector_type(4)));

#define NB 4096
#define DD 128
static constexpr float EPSF = 1e-8f;
static constexpr float TEMP = 11.313708498984760390f; // sqrt(128)

static __device__ __forceinline__ short f2bf(float f) {
    __hip_bfloat16 h = __float2bfloat16(f);
    union { __hip_bfloat16 h; short s; } u; u.h = h; return u.s;
}
static __device__ __forceinline__ float bf2f(short s) {
    union { __hip_bfloat16 h; short s; } u; u.s = s;
    return __bfloat162float(u.h);
}

// Pack 8 consecutive fp32 -> bf16x8 fragment
static __device__ __forceinline__ short8 load_cvt8(const float* __restrict__ p) {
    float4 a = *(const float4*)p;
    float4 b = *(const float4*)(p + 4);
    short8 o;
    o[0] = f2bf(a.x); o[1] = f2bf(a.y); o[2] = f2bf(a.z); o[3] = f2bf(a.w);
    o[4] = f2bf(b.x); o[5] = f2bf(b.y); o[6] = f2bf(b.z); o[7] = f2bf(b.w);
    return o;
}

// Fragment-major offset for qn/kn: matrix row g (0..4095), k index kidx (0..127)
// layout: [g>>4][kidx>>5][(kidx>>3)&3 * 16 + (g&15)][kidx&7]
static __device__ __forceinline__ int frag_off(int g, int kidx) {
    return ((((g >> 4) * 4 + (kidx >> 5)) * 4 + ((kidx >> 3) & 3)) * 16
            + (g & 15)) * 8 + (kidx & 7);
}

// ---------------- projection + metric-normalize (MFMA, bf16) ----------------
// R4/R6/R8-passing version, unchanged. 512 blocks x 512 threads.
__global__ __launch_bounds__(512) void proj_kernel(
    const float* __restrict__ qp, const float* __restrict__ kp,
    const float* __restrict__ Wq, const float* __restrict__ bq,
    const float* __restrict__ Wk, const float* __restrict__ bk,
    __hip_bfloat16* __restrict__ qn, __hip_bfloat16* __restrict__ kn,
    float* __restrict__ rq, float* __restrict__ rk)
{
    int t = threadIdx.x;
    int b = blockIdx.x;                 // 0..511; 256 per matrix

    int which = b >> 8;
    int row0 = (b & 255) * 16;
    const float* x    = which ? kp : qp;
    const float* W    = which ? Wk : Wq;
    const float* bias = which ? bk : bq;
    short* outv = which ? (short*)kn : (short*)qn;
    float* outr = which ? rk : rq;

    int lane = t & 63, wid = t >> 6;    // 8 waves
    int m = lane & 15, quad = lane >> 4;
    int colb = wid * 16;                // wave col origin (8 waves x 16 cols)

    floatx4 acc = (floatx4){0.f, 0.f, 0.f, 0.f};

    #pragma unroll
    for (int ks = 0; ks < 4; ++ks) {
        int koff = ks * 32 + quad * 8;
        short8 af  = load_cvt8(x + (row0 + m) * DD + koff);
        short8 bfr = load_cvt8(W + (colb + m) * DD + koff);
        acc = __builtin_amdgcn_mfma_f32_16x16x32_bf16(af, bfr, acc, 0, 0, 0);
    }

    __shared__ float buf[8][16];
    __shared__ float nfb[16];

    float bv = bias[colb + m];

    #pragma unroll
    for (int r = 0; r < 4; ++r) {
        float v = acc[r] + bv;
        acc[r] = v;
        float p = v * v;
        p += __shfl_xor(p, 1); p += __shfl_xor(p, 2);
        p += __shfl_xor(p, 4); p += __shfl_xor(p, 8);
        if (m == 0) buf[wid][quad*4 + r] = p;
    }
    __syncthreads();
    if (t < 16) {
        float s = 0.f;
        #pragma unroll
        for (int w = 0; w < 8; ++w) s += buf[w][t];
        float fro = sqrtf(s*s*(1.0f/16384.0f) + s*(1.0f/64.0f) + 128.0f);
        float qnorm = sqrtf((s*s*(1.0f/128.0f) + s) / (fro + EPSF));
        nfb[t] = 1.0f / (qnorm + EPSF);
    }
    __syncthreads();

    #pragma unroll
    for (int r = 0; r < 4; ++r) {
        int lrow = quad*4 + r;              // block-local 0..15
        int g = row0 + lrow;                // global matrix row
        float nf = nfb[lrow];
        float v = acc[r] * nf;
        short sb = f2bf(v);
        outv[frag_off(g, colb + m)] = sb;
        float vf = bf2f(sb);
        float u = vf * vf;
        u += __shfl_xor(u, 1); u += __shfl_xor(u, 2);
        u += __shfl_xor(u, 4); u += __shfl_xor(u, 8);
        if (m == 0) buf[wid][lrow] = u;
    }
    __syncthreads();
    if (t < 16) {
        float s = 0.f;
        #pragma unroll
        for (int w = 0; w < 8; ++w) s += buf[w][t];
        outr[row0 + t] = s;
    }
}

// ---------------- scores: hybrid hold/recompute -----------------------------
// 256 blocks x 1024 threads (16 waves, bounds(1024,4) = 128-reg budget; R7
// proved anything tighter spills). Wave w owns cols [w*256, +256): 16 tiles.
// mfma(bfr, af): lane (m,quad) owns q-row (r0+m), k-cols colblk*16+quad*4+r.
//
// Measured trade (R2/R4 vs R6/R8): full-acc (hold 64 e, 0 reg headroom) ~40us;
// two-pass (hold 0, recompute 16 tiles) 44.4us; manual pipelining neutral
// (R8 == R6, compiler already pipelines ~1 deep). Hybrid: hold e for tiles
// 0-7 (32 regs), recompute only tiles 8-15. Pass B halves; live regs ~85 of
// 128 leaves the compiler real scheduling headroom; held-tile stores issue
// right after the inv barrier with no loads, overlapping pass B's first
// loads. Same op order per tile as R6/R8 -> bit-identical e.
__global__ __launch_bounds__(1024, 4) void score_rows(
    const __hip_bfloat16* __restrict__ qn, const __hip_bfloat16* __restrict__ kn,
    const float* __restrict__ rq, const float* __restrict__ rk,
    float* __restrict__ P)
{
    int lane = threadIdx.x & 63;
    int wid  = threadIdx.x >> 6;        // 0..15
    int m    = lane & 15;
    int quad = lane >> 4;

    int rowblk = blockIdx.x;            // 16 rows per block
    int r0 = rowblk * 16;
    int cb0 = wid * 16;                 // wave's first colblk (cols wid*256..)

    const short* qs  = (const short*)qn;
    const short* kks = (const short*)kn;

    // A fragments: 16 rows x K=128 (coalesced 1 KB loads)
    short8 af[4];
    #pragma unroll
    for (int k4 = 0; k4 < 4; ++k4)
        af[k4] = *(const short8*)(qs + ((rowblk*4 + k4)*64 + lane)*8);

    float rqv = rq[r0 + m];             // this lane's q-row |qn|^2

    // ---------------- pass A: all 16 tiles; hold e for tiles 0-7 ----------
    floatx4 eh[8];                      // held e (tiles 0..7), 32 regs
    float rs = 0.f;
    #pragma unroll
    for (int t = 0; t < 16; ++t) {
        int colblk = cb0 + t;
        short8 bfr[4];
        #pragma unroll
        for (int k4 = 0; k4 < 4; ++k4)
            bfr[k4] = *(const short8*)(kks + ((colblk*4 + k4)*64 + lane)*8);
        floatx4 a = (floatx4){0.f, 0.f, 0.f, 0.f};
        #pragma unroll
        for (int k4 = 0; k4 < 4; ++k4)
            a = __builtin_amdgcn_mfma_f32_16x16x32_bf16(bfr[k4], af[k4], a, 0, 0, 0);
        floatx4 rkv = *(const floatx4*)(rk + colblk*16 + quad*4);
        #pragma unroll
        for (int r = 0; r < 4; ++r) {
            float d2 = fmaf(-2.0f, a[r], rqv + rkv[r]);
            float d  = d2 > 0.0f ? __builtin_amdgcn_sqrtf(d2) : 0.0f;
            float e  = __expf(TEMP * __builtin_amdgcn_rcpf(1.0f + d));
            rs += e;
            if (t < 8) eh[t][r] = e;    // compile-time index (full unroll)
        }
    }

    // rs is partial over this lane's 64 cols; reduce across the 4 quads
    rs += __shfl_xor(rs, 16);
    rs += __shfl_xor(rs, 32);

    __shared__ float sums[16][16];
    __shared__ float inv[16];
    if (lane < 16) sums[wid][lane] = rs;   // quad==0 lanes: m = lane
    __syncthreads();
    if (threadIdx.x < 16) {
        float s = 0.f;
        #pragma unroll
        for (int w = 0; w < 16; ++w) s += sums[w][threadIdx.x];
        inv[threadIdx.x] = __builtin_amdgcn_rcpf(s + EPSF);
    }
    __syncthreads();

    float invv = inv[m];

    // held tiles: store immediately (no loads -> overlaps pass B's loads)
    #pragma unroll
    for (int t = 0; t < 8; ++t) {
        floatx4 o = eh[t] * invv;
        *(floatx4*)(P + (size_t)(r0 + m) * NB + (cb0 + t)*16 + quad*4) = o;
    }

    // ---------------- pass B: recompute tiles 8-15, scale, store ----------
    #pragma unroll
    for (int t = 8; t < 16; ++t) {
        int colblk = cb0 + t;
        short8 bfr[4];
        #pragma unroll
        for (int k4 = 0; k4 < 4; ++k4)
            bfr[k4] = *(const short8*)(kks + ((colblk*4 + k4)*64 + lane)*8);
        floatx4 a = (floatx4){0.f, 0.f, 0.f, 0.f};
        #pragma unroll
        for (int k4 = 0; k4 < 4; ++k4)
            a = __builtin_amdgcn_mfma_f32_16x16x32_bf16(bfr[k4], af[k4], a, 0, 0, 0);
        floatx4 rkv = *(const floatx4*)(rk + colblk*16 + quad*4);
        floatx4 o;
        #pragma unroll
        for (int r = 0; r < 4; ++r) {
            float d2 = fmaf(-2.0f, a[r], rqv + rkv[r]);
            float d  = d2 > 0.0f ? __builtin_amdgcn_sqrtf(d2) : 0.0f;
            float e  = __expf(TEMP * __builtin_amdgcn_rcpf(1.0f + d));
            o[r] = e * invv;
        }
        *(floatx4*)(P + (size_t)(r0 + m) * NB + colblk*16 + quad*4) = o;
    }
}

extern "C" void kernel_launch(void* const* d_in, const int* in_sizes, int n_in,
                              void* d_out, int out_size, void* d_ws, size_t ws_size,
                              hipStream_t stream) {
    const float* qp = (const float*)d_in[0];
    const float* kp = (const float*)d_in[1];
    const float* Wq = (const float*)d_in[2];
    const float* bq = (const float*)d_in[3];
    const float* Wk = (const float*)d_in[4];
    const float* bk = (const float*)d_in[5];
    float* P = (float*)d_out;

    char* ws = (char*)d_ws;
    __hip_bfloat16* qn = (__hip_bfloat16*)ws;                         // 1 MB
    __hip_bfloat16* kn = (__hip_bfloat16*)(ws + (size_t)NB*DD*2);     // 1 MB
    float* rq = (float*)(ws + (size_t)NB*DD*4);                       // 16 KB
    float* rk = (float*)(ws + (size_t)NB*DD*4 + (size_t)NB*4);        // 16 KB

    hipLaunchKernelGGL(proj_kernel, dim3(512), dim3(512), 0, stream,
                       qp, kp, Wq, bq, Wk, bk, qn, kn, rq, rk);
    hipLaunchKernelGGL(score_rows, dim3(256), dim3(1024), 0, stream,
                       qn, kn, rq, rk, P);
}